// Round 4
// baseline (871.717 us; speedup 1.0000x reference)
//
#include <hip/hip_runtime.h>
#include <math.h>

// Fully fused SNN forward (linearity collapse verified R1-R3, absmax 4.8e-7).
// R8 = R7 rerun (bench infra died twice; no counters). Kernel re-audited:
// no OOB (max W addr 100347 < 100352), no graph-capture violations.
// R7 theory: W via VMEM counted-wait pipeline. Evidence across R4-R6:
//  - VALU busy time invariant ~156us = padded FLOPs at scalar fp32 rate
//    (v_pk_fma_f32 = issue compression, NOT 2x rate).
//  - Stall ~95us survives 2x occupancy (R5) -> not a TLP deficit.
//  - R6 (W in LDS) is LDS-throughput-bound: 64 ds_read x ~12cyc = 768
//    LDS-cyc/CU/k > 400 VALU budget -> 271us. Reverted.
//  - Remaining common element: s_load W. SMEM returns OUT-OF-ORDER ->
//    every W use forces lgkmcnt(0), draining the ds_read stream too;
//    barrier-locked waves hit drains in phase (why R5 didn't help).
// Change: W rows loaded as uniform-address global_load_dwordx4 (VMEM is
// IN-ORDER -> counted vmcnt(N) waits -> pipelinable; HW merges same-addr
// lanes to 1 L1 txn; live W window 14KB L1-fits). Explicit 2-deep
// software pipeline, statically indexed (full unroll). A VGPR-zero is
// added to the address so uniformity analysis can't re-scalarize to
// s_load. Geometry = R4: 2 batches/block, 512 blocks (2/CU exact), r=4.
// Budget/CU/k: VALU 400cyc, LDS ~96cyc, L1 ~900B -> VALU-bound.

#define NSTEPS 100
#define NHID 100
#define KDIM 784
#define BKT 28        // 784 = 28 * 28 exact
#define NOUT 10

typedef float v2f __attribute__((ext_vector_type(2)));

// ---- tiny transpose: Wt[k][32*cg + i] = W1[25*cg + i][k], pad i>=25 with 0
__global__ __launch_bounds__(256)
void wt_transpose(const float* __restrict__ W1, float* __restrict__ Wt) {
  const int idx = blockIdx.x * 256 + threadIdx.x;   // 784*128 entries
  if (idx >= KDIM * 128) return;
  const int k = idx >> 7, s = idx & 127, cg = s >> 5, i = s & 31;
  const int j = 25 * cg + i;
  Wt[idx] = (i < 25) ? W1[(size_t)j * KDIM + k] : 0.0f;
}

#define LOADW(WB, KR)                                                   \
  {                                                                     \
    const float* wp = wgrp + (size_t)(KR) * 128;                        \
    _Pragma("unroll")                                                   \
    for (int q = 0; q < 7; ++q) WB[q] = *(const float4*)(wp + 4 * q);   \
  }

#define FMA_STEP(WB, KK)                                                \
  {                                                                     \
    const float4 xv = *(const float4*)&Xs[KK][4 * l];                   \
    const v2f xd0 = {xv.x, xv.x};                                       \
    const v2f xd1 = {xv.y, xv.y};                                       \
    const v2f xd2 = {xv.z, xv.z};                                       \
    const v2f xd3 = {xv.w, xv.w};                                       \
    _Pragma("unroll")                                                   \
    for (int c2 = 0; c2 < 12; ++c2) {                                   \
      const int q = c2 >> 1;                                            \
      const v2f wv = (c2 & 1) ? (v2f){WB[q].z, WB[q].w}                 \
                              : (v2f){WB[q].x, WB[q].y};                \
      acc2[0][c2] = __builtin_elementwise_fma(xd0, wv, acc2[0][c2]);    \
      acc2[1][c2] = __builtin_elementwise_fma(xd1, wv, acc2[1][c2]);    \
      acc2[2][c2] = __builtin_elementwise_fma(xd2, wv, acc2[2][c2]);    \
      acc2[3][c2] = __builtin_elementwise_fma(xd3, wv, acc2[3][c2]);    \
    }                                                                   \
    const float w24 = WB[6].x;                                          \
    accs[0] = fmaf(xv.x, w24, accs[0]);                                 \
    accs[1] = fmaf(xv.y, w24, accs[1]);                                 \
    accs[2] = fmaf(xv.z, w24, accs[2]);                                 \
    accs[3] = fmaf(xv.w, w24, accs[3]);                                 \
  }

__global__ __launch_bounds__(256, 2)
void snn_fused6(const float* __restrict__ X, const float* __restrict__ Wt,
                const float* __restrict__ wsyn1p, const float* __restrict__ b1,
                const float* __restrict__ wsyn2p, const float* __restrict__ W2,
                const float* __restrict__ b2, float* __restrict__ out) {
  __shared__ float Xs[BKT][256];     // 28.7 KB: k-major X tile (2 batches)
  __shared__ float Cs[2][25][106];   // scan chunk, stride 106 breaks conflicts
  __shared__ float zsh[2][NHID];

  const int tid = threadIdx.x;
  const int l   = tid & 63;
  const int cg  = tid >> 6;          // wave col group (lane-carried on purpose)
  const long b0 = 2L * blockIdx.x;

  // force-VGPR zero: keeps the W address out of uniformity analysis so the
  // backend emits global_load (in-order vmcnt), NOT s_load (OOO lgkmcnt(0)).
  int vzero;
  asm volatile("v_mov_b32 %0, 0" : "=v"(vzero));

  // staging identity: thread stages U-row `tid` (t>=100 clamped, discarded)
  const int sb = tid >> 7;
  const int st = ((tid & 127) < NSTEPS) ? (tid & 127) : (NSTEPS - 1);
  const float* __restrict__ Xrow = X + ((b0 + sb) * NSTEPS + st) * (size_t)KDIM;

  v2f  acc2[4][12];                  // rows 4l..4l+3, col pairs 0..23
  float accs[4];                     // col 24
#pragma unroll
  for (int i = 0; i < 4; ++i) {
    accs[i] = 0.0f;
#pragma unroll
    for (int c = 0; c < 12; ++c) acc2[i][c] = (v2f){0.0f, 0.0f};
  }

  float4 pf[7];                      // prefetched 28-float X row segment
#pragma unroll
  for (int q = 0; q < 7; ++q) pf[q] = *(const float4*)(Xrow + 4 * q);

  const float* __restrict__ wgrp = Wt + 32 * cg + vzero;  // VGPR address

  float4 wb0[7], wb1[7];             // 2-deep W pipeline (28 floats/row)
  LOADW(wb0, 0);

  for (int kt = 0; kt < KDIM; kt += BKT) {
    __syncthreads();                 // previous tile's LDS reads complete
#pragma unroll
    for (int q = 0; q < 7; ++q) {
      Xs[4 * q + 0][tid] = pf[q].x;
      Xs[4 * q + 1][tid] = pf[q].y;
      Xs[4 * q + 2][tid] = pf[q].z;
      Xs[4 * q + 3][tid] = pf[q].w;
    }
    __syncthreads();
    if (kt + BKT < KDIM) {
      const float* xp = Xrow + kt + BKT;
#pragma unroll
      for (int q = 0; q < 7; ++q) pf[q] = *(const float4*)(xp + 4 * q);
    }

#pragma unroll
    for (int k = 0; k < BKT; k += 2) {
      LOADW(wb1, kt + k + 1);        // row k+1 in flight over FMA(k)
      FMA_STEP(wb0, k);
      const int kr2 = (kt + k + 2 < KDIM) ? (kt + k + 2) : (KDIM - 1);
      LOADW(wb0, kr2);               // row k+2 (primes next tile at k=26)
      FMA_STEP(wb1, k + 1);
    }
  }

  // ---- fused scan epilogue: 4 chunks of 25 timesteps, 2 batches in parallel
  const float inv1 = 1.f / (1.f + expf(-wsyn1p[0]));
  const float inv2 = 1.f / (1.f + expf(-wsyn2p[0]));
  const int sb2 = tid >> 7;
  const int j   = tid & 127;
  const float bj = (j < NHID) ? b1[j] : 0.f;
  float S = 0.f, v1 = 0.f, s2 = 0.f, z = 0.f;
  float at = 0x1p-100f;              // 2^(t-100)

  for (int q = 0; q < 4; ++q) {
    __syncthreads();                 // previous chunk's reads complete
#pragma unroll
    for (int i = 0; i < 4; ++i) {
      const int r  = 4 * l + i;
      const int bb = r >> 7;
      const int t  = r & 127;
      const int tt = t - 25 * q;
      if (t < NSTEPS && tt >= 0 && tt < 25) {
        float* crow = &Cs[bb][tt][25 * cg];
#pragma unroll
        for (int c2 = 0; c2 < 12; ++c2) {
          crow[2 * c2 + 0] = acc2[i][c2].x;
          crow[2 * c2 + 1] = acc2[i][c2].y;
        }
        crow[24] = accs[i];
      }
    }
    __syncthreads();
    if (j < NHID) {
#pragma unroll
      for (int tt = 0; tt < 25; ++tt) {
        const float u = Cs[sb2][tt][j];
        S = S - S * inv1 + u;             // SynapseFilter 1 (h-space)
        const float h = S + bj;
        v1 = v1 + (h - v1) * 0.5f;        // LIF1, tau=2
        const float sp = (v1 >= 1.0f) ? 1.0f : 0.0f;
        v1 = v1 * (1.0f - sp);            // hard reset
        s2 = s2 - s2 * inv2 + sp;         // SynapseFilter 2
        z  = fmaf(at, s2, z);
        at *= 2.0f;
      }
    }
  }

  if (j < NHID) zsh[sb2][j] = z;
  __syncthreads();

  if (tid < 2 * NOUT) {
    const int bb = tid / NOUT;
    const int jo = tid % NOUT;
    float a = b2[jo];
    const float* __restrict__ wrow = W2 + jo * NHID;
#pragma unroll
    for (int jj = 0; jj < NHID; ++jj) a = fmaf(zsh[bb][jj], wrow[jj], a);
    out[(b0 + bb) * NOUT + jo] = a;
  }
}

extern "C" void kernel_launch(void* const* d_in, const int* in_sizes, int n_in,
                              void* d_out, int out_size, void* d_ws, size_t ws_size,
                              hipStream_t stream) {
  const float* x     = (const float*)d_in[0];
  const float* wsyn1 = (const float*)d_in[1];
  const float* W1    = (const float*)d_in[2];
  const float* b1    = (const float*)d_in[3];
  const float* wsyn2 = (const float*)d_in[4];
  const float* W2    = (const float*)d_in[5];
  const float* b2    = (const float*)d_in[6];
  float* out = (float*)d_out;
  float* Wt  = (float*)d_ws;   // 784 x 128 fp32 = 401 KB

  wt_transpose<<<dim3((KDIM * 128 + 255) / 256), dim3(256), 0, stream>>>(W1, Wt);
  snn_fused6<<<dim3(512), dim3(256), 0, stream>>>(x, Wt, wsyn1, b1, wsyn2, W2,
                                                  b2, out);
}